// Round 1
// baseline (70.894 us; speedup 1.0000x reference)
//
#include <hip/hip_runtime.h>

// Problem constants (from setup_inputs): B=16, F=1024 (32x32), Ci=64, Co=64, K=4, R=1.
#define CI 64
#define CO 64
#define B_ 16
#define F_ 1024
#define W_IMG 32
#define KK 4
#define NPAT 16
#define BLOCKS_PER_PAT 32
#define PAIRS_PER_PAT 1024          // B * OH * OW = 16*8*8
#define PAIRS_PER_BLOCK (PAIRS_PER_PAT / BLOCKS_PER_PAT)   // 32
#define PAIRS_PER_WAVE (PAIRS_PER_BLOCK / 4)               // 8

// out[b, h*32+w, co] = log( sum_ci exp(ll[b,f,ci]) * exp(logits[co,ci,kh,kw]) )
//                      - log( sum_ci exp(logits[co,ci,kh,kw]) ),  kh=h%4, kw=w%4.
__global__ __launch_bounds__(256, 2) void sumconv_kernel(
    const float* __restrict__ ll,
    const float* __restrict__ logits,
    float* __restrict__ out)
{
    __shared__ float Wl[CI * CO];      // exp(logits)  [ci][co]
    __shared__ float part[4 * CO];     // partial column sums [quarter][co]
    __shared__ float lsum_s[CO];       // log(sum_ci exp(logits)) per co
    __shared__ float p_lds[4][CI];     // per-wave broadcast row of exp(ll)

    const int tid   = threadIdx.x;
    const int lane  = tid & 63;
    const int wv    = tid >> 6;
    const int bid   = blockIdx.x;
    const int pat   = bid & (NPAT - 1);     // kh*4 + kw
    const int chunk = bid >> 4;             // 0..31

    // ---- Phase A: weights. thread = (co=lane, ci-quarter=wv) ----
    {
        const int co = lane;
        // logits[co][ci][kh][kw][0] -> offset co*1024 + ci*16 + pat
        const float* lg = logits + co * (CI * KK * KK) + pat;
        float psum = 0.f;
        #pragma unroll
        for (int i = 0; i < 16; ++i) {
            const int ci = wv * 16 + i;
            const float e = __expf(lg[ci * (KK * KK)]);
            Wl[ci * CO + co] = e;           // bank = co%32 -> 2-way (free)
            psum += e;
        }
        part[wv * CO + co] = psum;
    }
    __syncthreads();
    if (wv == 0) {
        const float tot = (part[lane] + part[CO + lane])
                        + (part[2 * CO + lane] + part[3 * CO + lane]);
        lsum_s[lane] = __logf(tot);
    }
    __syncthreads();

    // ---- Per-wave: weights into registers (lane = co) ----
    float wreg[CI];
    #pragma unroll
    for (int ci = 0; ci < CI; ++ci) wreg[ci] = Wl[ci * CO + lane];
    const float lsum = lsum_s[lane];

    const int kh = pat >> 2;
    const int kw = pat & 3;

    // ---- Pair loop: each wave handles PAIRS_PER_WAVE (b,f) positions ----
    #pragma unroll 1
    for (int j = 0; j < PAIRS_PER_WAVE; ++j) {
        const int pr = chunk * PAIRS_PER_BLOCK + wv * PAIRS_PER_WAVE + j;
        const int b  = pr >> 6;             // 16
        const int oh = (pr >> 3) & 7;       // 8
        const int ow = pr & 7;              // 8
        const int f  = (oh * 4 + kh) * W_IMG + (ow * 4 + kw);
        const int idx = (b * F_ + f) * CI + lane;   // lane = ci for load, co for store

        const float x = ll[idx];            // coalesced 256 B
        const float p = __expf(x);
        p_lds[wv][lane] = p;                // same-wave DS ops are pipe-ordered

        float a0 = 0.f, a1 = 0.f, a2 = 0.f, a3 = 0.f;
        #pragma unroll
        for (int ci = 0; ci < CI; ci += 4) {
            const float4 pv = *reinterpret_cast<const float4*>(&p_lds[wv][ci]); // broadcast b128
            a0 = fmaf(pv.x, wreg[ci + 0], a0);
            a1 = fmaf(pv.y, wreg[ci + 1], a1);
            a2 = fmaf(pv.z, wreg[ci + 2], a2);
            a3 = fmaf(pv.w, wreg[ci + 3], a3);
        }
        out[idx] = __logf((a0 + a1) + (a2 + a3)) - lsum;   // coalesced 256 B
    }
}

extern "C" void kernel_launch(void* const* d_in, const int* in_sizes, int n_in,
                              void* d_out, int out_size, void* d_ws, size_t ws_size,
                              hipStream_t stream) {
    const float* ll     = (const float*)d_in[0];
    const float* logits = (const float*)d_in[1];
    float* out          = (float*)d_out;
    sumconv_kernel<<<dim3(NPAT * BLOCKS_PER_PAT), dim3(256), 0, stream>>>(ll, logits, out);
}

// Round 2
// 64.969 us; speedup vs baseline: 1.0912x; 1.0912x over previous
//
#include <hip/hip_runtime.h>

// Problem: B=16, F=1024 (32x32 image), Ci=64, Co=64, K=4, R=1.
// out[b, h*32+w, co] = log( sum_ci exp(ll[b,f,ci]) * exp(logits[co,ci,kh,kw]) )
//                      - log( sum_ci exp(logits[co,ci,kh,kw]) ),  kh=h%4, kw=w%4.
#define CI 64
#define CO 64
#define F_ 1024
#define KK 4
#define NPAT 16

// ---------------- kernel 1: prep (runs once, 16 blocks) ----------------
// E[pat][ci][co] = exp(logits[co][ci][kh][kw]);  Lsum[pat][co] = log(sum_ci E)
__global__ __launch_bounds__(256) void prep_kernel(
    const float* __restrict__ logits, float* __restrict__ E, float* __restrict__ Lsum)
{
    __shared__ float part[4 * CO];
    const int pat = blockIdx.x;              // 0..15 = kh*4+kw
    const int t   = threadIdx.x;
    const int co  = t & 63;
    const int q   = t >> 6;
    const float* lg = logits + co * (CI * KK * KK) + pat;  // stride ci = 16 floats
    float psum = 0.f;
    #pragma unroll
    for (int i = 0; i < 16; ++i) {
        const int ci = q * 16 + i;
        const float e = __expf(lg[ci * (KK * KK)]);
        E[pat * (CI * CO) + ci * CO + co] = e;             // coalesced in co
        psum += e;
    }
    part[q * CO + co] = psum;
    __syncthreads();
    if (q == 0) {
        const float tot = (part[co] + part[CO + co]) + (part[2 * CO + co] + part[3 * CO + co]);
        Lsum[pat * CO + co] = __logf(tot);
    }
}

// ---------------- kernel 2: main (1024 blocks, no barriers) ----------------
// Wave layout: lane = co (for compute/store) = ci (for ll load).
// Each wave owns 4 (b,oh,ow) positions of one pattern; 4 waves/block.
__global__ __launch_bounds__(256, 4) void main_kernel(
    const float* __restrict__ ll, const float* __restrict__ E,
    const float* __restrict__ Lsum, float* __restrict__ out)
{
    __shared__ float p_lds[4][4][CI];        // [wave][pair][ci] — 4 KB
    const int tid   = threadIdx.x;
    const int lane  = tid & 63;
    const int wv    = tid >> 6;
    const int bid   = blockIdx.x;            // 1024
    const int pat   = bid & (NPAT - 1);
    const int chunk = bid >> 4;              // 0..63
    const int kh = pat >> 2, kw = pat & 3;

    // ---- issue the 4 HBM loads first (longest latency) ----
    int   idx[4];
    float p[4];
    #pragma unroll
    for (int j = 0; j < 4; ++j) {
        const int pr = (chunk << 4) + (wv << 2) + j;   // 0..1023 = b*64 + oh*8 + ow
        const int b  = pr >> 6;
        const int oh = (pr >> 3) & 7;
        const int ow = pr & 7;
        const int f  = (oh * 4 + kh) * 32 + (ow * 4 + kw);
        idx[j] = (b * F_ + f) * CI + lane;             // coalesced 256 B / wave
        p[j]   = ll[idx[j]];
    }

    // ---- weights: lane = co, coalesced loads from L2-hot E ----
    const float* Ep = E + pat * (CI * CO) + lane;
    float wreg[CI];
    #pragma unroll
    for (int ci = 0; ci < CI; ++ci) wreg[ci] = Ep[ci * CO];
    const float lsum = Lsum[pat * CO + lane];

    // ---- exp + wave-private LDS broadcast stage ----
    #pragma unroll
    for (int j = 0; j < 4; ++j) {
        p[j] = __expf(p[j]);
        p_lds[wv][j][lane] = p[j];
    }
    __builtin_amdgcn_wave_barrier();         // forbid hoisting ds_reads above the writes

    // ---- 8 independent FMA chains over ci ----
    float a0[4] = {0.f, 0.f, 0.f, 0.f}, a1[4] = {0.f, 0.f, 0.f, 0.f};
    #pragma unroll
    for (int ci = 0; ci < CI; ci += 4) {
        #pragma unroll
        for (int j = 0; j < 4; ++j) {
            const float4 pv = *reinterpret_cast<const float4*>(&p_lds[wv][j][ci]); // broadcast b128
            a0[j] = fmaf(pv.x, wreg[ci + 0], a0[j]);
            a1[j] = fmaf(pv.y, wreg[ci + 1], a1[j]);
            a0[j] = fmaf(pv.z, wreg[ci + 2], a0[j]);
            a1[j] = fmaf(pv.w, wreg[ci + 3], a1[j]);
        }
    }
    #pragma unroll
    for (int j = 0; j < 4; ++j)
        out[idx[j]] = __logf(a0[j] + a1[j]) - lsum;    // coalesced 256 B / wave
}

extern "C" void kernel_launch(void* const* d_in, const int* in_sizes, int n_in,
                              void* d_out, int out_size, void* d_ws, size_t ws_size,
                              hipStream_t stream) {
    const float* ll     = (const float*)d_in[0];
    const float* logits = (const float*)d_in[1];
    float* out  = (float*)d_out;
    float* E    = (float*)d_ws;                        // 16*64*64 floats = 256 KB
    float* Lsum = E + NPAT * CI * CO;                  // 16*64 floats
    prep_kernel<<<dim3(NPAT), dim3(256), 0, stream>>>(logits, E, Lsum);
    main_kernel<<<dim3(1024), dim3(256), 0, stream>>>(ll, E, Lsum, out);
}

// Round 3
// 64.061 us; speedup vs baseline: 1.1067x; 1.0142x over previous
//
#include <hip/hip_runtime.h>

// Problem: B=16, F=1024 (32x32 image), Ci=64, Co=64, K=4, R=1.
// out[b, h*32+w, co] = log( sum_ci exp(ll[b,f,ci]) * exp(logits[co,ci,kh,kw]) )
//                      - log( sum_ci exp(logits[co,ci,kh,kw]) ),  kh=h%4, kw=w%4.
#define CI 64
#define CO 64
#define F_ 1024
#define KK 4
#define NPAT 16

__device__ __forceinline__ float bcast(float v, int l) {
    return __int_as_float(__builtin_amdgcn_readlane(__float_as_int(v), l));
}

// ---------------- kernel 1: prep (64 blocks) ----------------
// E2[pat][g][co][k] = exp(logits[co][ci=4g+k][kh][kw])   (float4-friendly for main)
__global__ __launch_bounds__(256) void prep_kernel(
    const float* __restrict__ logits, float* __restrict__ E)
{
    const int pat = blockIdx.x >> 2;         // 0..15
    const int q   = blockIdx.x & 3;          // ci quarter
    const int t   = threadIdx.x;
    const int co  = t & 63;
    const int i   = t >> 6;                  // 0..3
    #pragma unroll
    for (int k = 0; k < 4; ++k) {
        const int ci = q * 16 + i * 4 + k;
        const float e = __expf(logits[co * (CI * KK * KK) + ci * (KK * KK) + pat]);
        E[pat * (CI * CO) + (ci >> 2) * (CO * 4) + co * 4 + (ci & 3)] = e;
    }
}

// ---------------- kernel 2: main (1024 blocks, no LDS, no barriers) ----------------
// lane = co (compute/store) = ci (ll load). Each wave: 4 positions of one pattern.
__global__ __launch_bounds__(256, 4) void main_kernel(
    const float* __restrict__ ll, const float* __restrict__ E,
    float* __restrict__ out)
{
    const int tid   = threadIdx.x;
    const int lane  = tid & 63;
    const int wv    = tid >> 6;
    const int bid   = blockIdx.x;            // 1024
    const int pat   = bid & (NPAT - 1);
    const int chunk = bid >> 4;              // 0..63
    const int kh = pat >> 2, kw = pat & 3;

    // ---- issue the 4 HBM loads first (longest latency) ----
    int   idx[4];
    float p[4];
    #pragma unroll
    for (int j = 0; j < 4; ++j) {
        const int pr = (chunk << 4) + (wv << 2) + j;   // b*64 + oh*8 + ow
        const int b  = pr >> 6;
        const int oh = (pr >> 3) & 7;
        const int ow = pr & 7;
        const int f  = (oh * 4 + kh) * 32 + (ow * 4 + kw);
        idx[j] = (b * F_ + f) * CI + lane;             // coalesced 256 B / wave
        p[j]   = ll[idx[j]];
    }

    // ---- weights: 16 coalesced float4 loads (L2-hot), lane = co ----
    float4 wv4[16];
    const float4* Ep4 = reinterpret_cast<const float4*>(E + pat * (CI * CO)) + lane;
    #pragma unroll
    for (int g = 0; g < 16; ++g) wv4[g] = Ep4[g * CO];
    float wreg[CI];
    #pragma unroll
    for (int g = 0; g < 16; ++g) {
        wreg[4 * g + 0] = wv4[g].x; wreg[4 * g + 1] = wv4[g].y;
        wreg[4 * g + 2] = wv4[g].z; wreg[4 * g + 3] = wv4[g].w;
    }

    // ---- lsum = log(sum_ci E[ci][co]) computed in-register ----
    float ts[8];
    #pragma unroll
    for (int i = 0; i < 8; ++i)
        ts[i] = (wreg[i] + wreg[i + 8]) + (wreg[i + 16] + wreg[i + 24])
              + (wreg[i + 32] + wreg[i + 40]) + (wreg[i + 48] + wreg[i + 56]);
    const float lsum = __logf(((ts[0] + ts[1]) + (ts[2] + ts[3]))
                            + ((ts[4] + ts[5]) + (ts[6] + ts[7])));

    // ---- exp, then broadcast via v_readlane (VALU pipe, no LDS) ----
    #pragma unroll
    for (int j = 0; j < 4; ++j) p[j] = __expf(p[j]);

    float a0[4] = {0.f,0.f,0.f,0.f}, a1[4] = {0.f,0.f,0.f,0.f};
    float a2[4] = {0.f,0.f,0.f,0.f}, a3[4] = {0.f,0.f,0.f,0.f};
    #pragma unroll
    for (int ci = 0; ci < CI; ci += 4) {
        #pragma unroll
        for (int j = 0; j < 4; ++j) {
            a0[j] = fmaf(bcast(p[j], ci + 0), wreg[ci + 0], a0[j]);
            a1[j] = fmaf(bcast(p[j], ci + 1), wreg[ci + 1], a1[j]);
            a2[j] = fmaf(bcast(p[j], ci + 2), wreg[ci + 2], a2[j]);
            a3[j] = fmaf(bcast(p[j], ci + 3), wreg[ci + 3], a3[j]);
        }
    }
    #pragma unroll
    for (int j = 0; j < 4; ++j)
        out[idx[j]] = __logf((a0[j] + a1[j]) + (a2[j] + a3[j])) - lsum;  // coalesced
}

extern "C" void kernel_launch(void* const* d_in, const int* in_sizes, int n_in,
                              void* d_out, int out_size, void* d_ws, size_t ws_size,
                              hipStream_t stream) {
    const float* ll     = (const float*)d_in[0];
    const float* logits = (const float*)d_in[1];
    float* out = (float*)d_out;
    float* E   = (float*)d_ws;               // 16*64*64 floats = 256 KB
    prep_kernel<<<dim3(64), dim3(256), 0, stream>>>(logits, E);
    main_kernel<<<dim3(1024), dim3(256), 0, stream>>>(ll, E, out);
}